// Round 4
// baseline (208.488 us; speedup 1.0000x reference)
//
#include <hip/hip_runtime.h>
#include <hip/hip_cooperative_groups.h>

// NegLogLikelihood:
//   mean, cov = split(output, 2, axis=0)   each [4096, 2048] fp32
//   logdet = sum(log(cov))                 scalar
//   out = -((mean - target)^2 / cov + logdet)
//
// Primary path: single fused cooperative kernel (cov kept in registers
// across grid.sync, agent-scope atomics for partials).
// Fallback path (if hipLaunchCooperativeKernel returns an error, e.g.
// rejected under graph capture): the proven 2-kernel version from round 2.

#define N_ELEMS (4096 * 2048)              // per-half element count
#define N_VEC4  (N_ELEMS / 4)              // 2097152 float4s

// ---- fused config: 512 blocks x 512 threads = 2 blocks/CU needed ----
#define FNB 512
#define FNT 512
#define FIT (N_VEC4 / (FNB * FNT))         // 8

// ---- fallback config (round-2 proven) ----
#define BNB 2048
#define BNT 256
#define BIT (N_VEC4 / (BNB * BNT))         // 4

__global__ __launch_bounds__(FNT, 4) void nll_fused_kernel(
    const float* __restrict__ mean, const float* __restrict__ cov,
    const float* __restrict__ target, float* __restrict__ partials,
    float* __restrict__ out) {
    const float4* __restrict__ c4 = reinterpret_cast<const float4*>(cov);
    const int idx = blockIdx.x * FNT + threadIdx.x;
    const int stride = FNB * FNT;

    // ---- Phase A: log-sum over cov; keep cov values in registers ----
    float4 cv[FIT];
    float s = 0.0f;
    #pragma unroll
    for (int it = 0; it < FIT; ++it) {
        cv[it] = c4[idx + it * stride];
        s += __logf(cv[it].x) + __logf(cv[it].y) +
             __logf(cv[it].z) + __logf(cv[it].w);
    }
    #pragma unroll
    for (int off = 32; off > 0; off >>= 1)
        s += __shfl_down(s, off, 64);
    __shared__ float wsumA[FNT / 64];
    if ((threadIdx.x & 63) == 0) wsumA[threadIdx.x >> 6] = s;
    __syncthreads();
    if (threadIdx.x == 0) {
        float b = 0.0f;
        #pragma unroll
        for (int w = 0; w < FNT / 64; ++w) b += wsumA[w];
        // agent-scope release store: visible across XCD L2s
        __hip_atomic_store(&partials[blockIdx.x], b,
                           __ATOMIC_RELEASE, __HIP_MEMORY_SCOPE_AGENT);
    }

    cooperative_groups::this_grid().sync();

    // ---- Phase B: reduce 512 partials (one per thread) ----
    float p = __hip_atomic_load(&partials[threadIdx.x],
                                __ATOMIC_RELAXED, __HIP_MEMORY_SCOPE_AGENT);
    #pragma unroll
    for (int off = 32; off > 0; off >>= 1)
        p += __shfl_down(p, off, 64);
    __shared__ float wsumB[FNT / 64];
    if ((threadIdx.x & 63) == 0) wsumB[threadIdx.x >> 6] = p;
    __syncthreads();
    float logdet = 0.0f;
    #pragma unroll
    for (int w = 0; w < FNT / 64; ++w) logdet += wsumB[w];

    // ---- elementwise map (cov already in registers) ----
    const float4* __restrict__ m4 = reinterpret_cast<const float4*>(mean);
    const float4* __restrict__ t4 = reinterpret_cast<const float4*>(target);
    float4* __restrict__ o4 = reinterpret_cast<float4*>(out);
    #pragma unroll
    for (int it = 0; it < FIT; ++it) {
        int i = idx + it * stride;
        float4 m = m4[i];
        float4 t = t4[i];
        float4 c = cv[it];
        float4 r;
        float ex = m.x - t.x;
        float ey = m.y - t.y;
        float ez = m.z - t.z;
        float ew = m.w - t.w;
        r.x = -(ex * ex * __builtin_amdgcn_rcpf(c.x) + logdet);
        r.y = -(ey * ey * __builtin_amdgcn_rcpf(c.y) + logdet);
        r.z = -(ez * ez * __builtin_amdgcn_rcpf(c.z) + logdet);
        r.w = -(ew * ew * __builtin_amdgcn_rcpf(c.w) + logdet);
        o4[i] = r;
    }
}

// ================= fallback: proven round-2 two-kernel path =================

__global__ __launch_bounds__(BNT) void logdet_partial_kernel(
    const float* __restrict__ cov, float* __restrict__ partials) {
    const float4* __restrict__ c4 = reinterpret_cast<const float4*>(cov);
    int idx = blockIdx.x * blockDim.x + threadIdx.x;
    const int stride = BNB * BNT;

    float s = 0.0f;
    #pragma unroll
    for (int it = 0; it < BIT; ++it) {
        float4 v = c4[idx + it * stride];
        s += __logf(v.x) + __logf(v.y) + __logf(v.z) + __logf(v.w);
    }
    #pragma unroll
    for (int off = 32; off > 0; off >>= 1)
        s += __shfl_down(s, off, 64);
    __shared__ float wsum[4];
    if ((threadIdx.x & 63) == 0) wsum[threadIdx.x >> 6] = s;
    __syncthreads();
    if (threadIdx.x == 0)
        partials[blockIdx.x] = (wsum[0] + wsum[1]) + (wsum[2] + wsum[3]);
}

__global__ __launch_bounds__(BNT) void nll_elem_kernel(
    const float* __restrict__ mean, const float* __restrict__ cov,
    const float* __restrict__ target, const float* __restrict__ partials,
    float* __restrict__ out) {
    const float4* __restrict__ p4 = reinterpret_cast<const float4*>(partials);
    float4 pa = p4[threadIdx.x];
    float4 pb = p4[threadIdx.x + 256];
    float s = (pa.x + pa.y) + (pa.z + pa.w) + (pb.x + pb.y) + (pb.z + pb.w);
    #pragma unroll
    for (int off = 32; off > 0; off >>= 1)
        s += __shfl_down(s, off, 64);
    __shared__ float wsum[4];
    if ((threadIdx.x & 63) == 0) wsum[threadIdx.x >> 6] = s;
    __syncthreads();
    const float logdet = (wsum[0] + wsum[1]) + (wsum[2] + wsum[3]);

    const float4* __restrict__ m4 = reinterpret_cast<const float4*>(mean);
    const float4* __restrict__ c4 = reinterpret_cast<const float4*>(cov);
    const float4* __restrict__ t4 = reinterpret_cast<const float4*>(target);
    float4* __restrict__ o4 = reinterpret_cast<float4*>(out);

    int idx = blockIdx.x * blockDim.x + threadIdx.x;
    const int stride = BNB * BNT;

    #pragma unroll
    for (int it = 0; it < BIT; ++it) {
        int i = idx + it * stride;
        float4 m = m4[i];
        float4 c = c4[i];
        float4 t = t4[i];
        float4 r;
        float ex = m.x - t.x;
        float ey = m.y - t.y;
        float ez = m.z - t.z;
        float ew = m.w - t.w;
        r.x = -(ex * ex * __builtin_amdgcn_rcpf(c.x) + logdet);
        r.y = -(ey * ey * __builtin_amdgcn_rcpf(c.y) + logdet);
        r.z = -(ez * ez * __builtin_amdgcn_rcpf(c.z) + logdet);
        r.w = -(ew * ew * __builtin_amdgcn_rcpf(c.w) + logdet);
        o4[i] = r;
    }
}

extern "C" void kernel_launch(void* const* d_in, const int* in_sizes, int n_in,
                              void* d_out, int out_size, void* d_ws, size_t ws_size,
                              hipStream_t stream) {
    const float* output = (const float*)d_in[0];   // [8192, 2048]
    const float* target = (const float*)d_in[1];   // [4096, 2048]
    const float* mean = output;
    const float* cov  = output + N_ELEMS;
    float* out = (float*)d_out;
    float* partials = (float*)d_ws;

    void* args[] = {(void*)&mean, (void*)&cov, (void*)&target,
                    (void*)&partials, (void*)&out};
    hipError_t e = hipLaunchCooperativeKernel((const void*)nll_fused_kernel,
                                              dim3(FNB), dim3(FNT), args, 0,
                                              stream);
    if (e != hipSuccess) {
        (void)hipGetLastError();   // clear sticky error; fall back to 2-kernel path
        logdet_partial_kernel<<<BNB, BNT, 0, stream>>>(cov, partials);
        nll_elem_kernel<<<BNB, BNT, 0, stream>>>(mean, cov, target, partials, out);
    }
}

// Round 8
// 131.964 us; speedup vs baseline: 1.5799x; 1.5799x over previous
//
#include <hip/hip_runtime.h>

// NegLogLikelihood:
//   mean, cov = split(output, 2, axis=0)   each [4096, 2048] fp32
//   logdet = sum(log(cov))                 scalar
//   out = -((mean - target)^2 / cov + logdet)
//
// Two-kernel structure (kernel boundary = the cheap grid barrier; round-4
// showed cooperative grid.sync costs ~60 µs of stall + L2 writeback on
// this stack, and the compiler won't keep values in VGPRs across it).
//   k1: per-block log-sum partials -> d_ws[0..1023]
//   k2: block-redundant reduce of 1024 partials + elementwise map,
//       NON-TEMPORAL stores for out (keeps cov L3-resident for k2's re-read)

#define N_ELEMS (4096 * 2048)              // per-half element count
#define N_VEC4  (N_ELEMS / 4)              // 2097152 float4s

#define K1_NB 1024
#define K1_NT 256
#define K1_IT (N_VEC4 / (K1_NB * K1_NT))   // 8

#define K2_NB 2048
#define K2_NT 256
#define K2_IT (N_VEC4 / (K2_NB * K2_NT))   // 4

// native clang vector type: accepted by __builtin_nontemporal_store
// (HIP's float4 is a class and is rejected — round-5 compile error)
typedef float f32x4 __attribute__((ext_vector_type(4)));

__global__ __launch_bounds__(K1_NT) void logdet_partial_kernel(
    const float* __restrict__ cov, float* __restrict__ partials) {
    const float4* __restrict__ c4 = reinterpret_cast<const float4*>(cov);
    int idx = blockIdx.x * K1_NT + threadIdx.x;
    const int stride = K1_NB * K1_NT;

    float s = 0.0f;
    #pragma unroll
    for (int it = 0; it < K1_IT; ++it) {
        float4 v = c4[idx + it * stride];
        s += __logf(v.x) + __logf(v.y) + __logf(v.z) + __logf(v.w);
    }
    #pragma unroll
    for (int off = 32; off > 0; off >>= 1)
        s += __shfl_down(s, off, 64);
    __shared__ float wsum[4];
    if ((threadIdx.x & 63) == 0) wsum[threadIdx.x >> 6] = s;
    __syncthreads();
    if (threadIdx.x == 0)
        partials[blockIdx.x] = (wsum[0] + wsum[1]) + (wsum[2] + wsum[3]);
}

__global__ __launch_bounds__(K2_NT) void nll_elem_kernel(
    const float* __restrict__ mean, const float* __restrict__ cov,
    const float* __restrict__ target, const float* __restrict__ partials,
    float* __restrict__ out) {
    // --- block-redundant reduce of 1024 partials (4 KB, L2-hot) ---
    const float4* __restrict__ p4 = reinterpret_cast<const float4*>(partials);
    float4 pa = p4[threadIdx.x];               // 256 threads x 4 = 1024
    float s = (pa.x + pa.y) + (pa.z + pa.w);
    #pragma unroll
    for (int off = 32; off > 0; off >>= 1)
        s += __shfl_down(s, off, 64);
    __shared__ float wsum[4];
    if ((threadIdx.x & 63) == 0) wsum[threadIdx.x >> 6] = s;
    __syncthreads();
    const float logdet = (wsum[0] + wsum[1]) + (wsum[2] + wsum[3]);

    // --- elementwise map ---
    const float4* __restrict__ m4 = reinterpret_cast<const float4*>(mean);
    const float4* __restrict__ c4 = reinterpret_cast<const float4*>(cov);
    const float4* __restrict__ t4 = reinterpret_cast<const float4*>(target);
    f32x4* __restrict__ o4 = reinterpret_cast<f32x4*>(out);

    int idx = blockIdx.x * K2_NT + threadIdx.x;
    const int stride = K2_NB * K2_NT;

    #pragma unroll
    for (int it = 0; it < K2_IT; ++it) {
        int i = idx + it * stride;
        float4 m = m4[i];
        float4 c = c4[i];
        float4 t = t4[i];
        float ex = m.x - t.x;
        float ey = m.y - t.y;
        float ez = m.z - t.z;
        float ew = m.w - t.w;
        f32x4 r;
        // v_rcp_f32 (~1e-7 rel err); term <= ~20 vs threshold 1.4e5
        r.x = -(ex * ex * __builtin_amdgcn_rcpf(c.x) + logdet);
        r.y = -(ey * ey * __builtin_amdgcn_rcpf(c.y) + logdet);
        r.z = -(ez * ez * __builtin_amdgcn_rcpf(c.z) + logdet);
        r.w = -(ew * ew * __builtin_amdgcn_rcpf(c.w) + logdet);
        // non-temporal: out is never re-read by these kernels; don't evict
        // cov/mean/target from L2/L3 with write-allocate traffic
        __builtin_nontemporal_store(r, &o4[i]);
    }
}

extern "C" void kernel_launch(void* const* d_in, const int* in_sizes, int n_in,
                              void* d_out, int out_size, void* d_ws, size_t ws_size,
                              hipStream_t stream) {
    const float* output = (const float*)d_in[0];   // [8192, 2048]
    const float* target = (const float*)d_in[1];   // [4096, 2048]
    const float* mean = output;
    const float* cov  = output + N_ELEMS;
    float* out = (float*)d_out;
    float* partials = (float*)d_ws;   // 1024 floats; every slot written by k1

    logdet_partial_kernel<<<K1_NB, K1_NT, 0, stream>>>(cov, partials);
    nll_elem_kernel<<<K2_NB, K2_NT, 0, stream>>>(mean, cov, target, partials, out);
}